// Round 14
// baseline (111.780 us; speedup 1.0000x reference)
//
#include <hip/hip_runtime.h>

#define D_MODEL 256
#define NH 8
#define DK 32
#define SEQ 4096
#define BATCH 2
#define M_ROWS (BATCH * SEQ)  // 8192
#define QS2 0.25503486f  // (1/sqrt(32))*log2(e): softmax scale + exp->exp2, folded into Q

typedef __attribute__((ext_vector_type(8))) short bf16x8;
typedef __attribute__((ext_vector_type(4))) short s16x4;
typedef __attribute__((ext_vector_type(4))) float f32x4;
typedef __attribute__((ext_vector_type(16))) float f32x16;

static __device__ __forceinline__ short f2bf(float f) {
    unsigned u = __float_as_uint(f);
    u += 0x7fff + ((u >> 16) & 1);  // RNE
    return (short)(u >> 16);
}

// ---------------- fp32 -> bf16 converts: x (2048 blk) + 4 weights (256 blk), one launch ----------------
__global__ void cvt_all(const float* __restrict__ x, short* __restrict__ xb,
                        const float* __restrict__ W0, const float* __restrict__ W1,
                        const float* __restrict__ W2, const float* __restrict__ W3,
                        short* __restrict__ D0, short* __restrict__ D1,
                        short* __restrict__ D2, short* __restrict__ D3) {
    const int blk = blockIdx.x;
    const float* s;
    short* d;
    int i;
    if (blk < 2048) {
        s = x; d = xb; i = blk * blockDim.x + threadIdx.x;
    } else {
        const int seg = (blk - 2048) >> 6;
        i = ((blk - 2048) & 63) * blockDim.x + threadIdx.x;
        s = seg == 0 ? W0 : seg == 1 ? W1 : seg == 2 ? W2 : W3;
        d = seg == 0 ? D0 : seg == 1 ? D1 : seg == 2 ? D2 : D3;
    }
    float4 v = reinterpret_cast<const float4*>(s)[i];
    s16x4 o;
    o.x = f2bf(v.x); o.y = f2bf(v.y); o.z = f2bf(v.z); o.w = f2bf(v.w);
    reinterpret_cast<s16x4*>(d)[i] = o;
}

// ---------------- QKV projection (R13-proven, frozen) ----------------
// Q: [bh][seq][32] bf16 pre-scaled by QS2.
// K: Kblk[bh][t][s*2+hh][lane][8]: granule(lane l) = K[t*64+s*32+(l&31)][d = 16*hh+8*(l>>5) .. +8]
// V: Vblk[bh][t][c][lane][8]: elem j = V[t*64 + 16c + 8*(j>>2) + 4*(l>>5) + (j&3)][d = l&31]
__global__ __launch_bounds__(256) void qkv_gemm(
    const short* __restrict__ A,
    const short* __restrict__ Wqb, const short* __restrict__ Wkb, const short* __restrict__ Wvb,
    const float* __restrict__ bq, const float* __restrict__ bk, const float* __restrict__ bv,
    short* __restrict__ Qb, short* __restrict__ Kblk, short* __restrict__ Vblk)
{
    const int ct = blockIdx.x;   // 0..11 = mat*4 + coltile
    const int rt = blockIdx.y;   // 0..127
    const int tid = threadIdx.x;
    const int w = tid >> 6, l = tid & 63, l15 = l & 15, g = l >> 4;
    const int mat = ct >> 2;
    const int colbase = (ct & 3) * 64;
    const short* W = mat == 0 ? Wqb : mat == 1 ? Wkb : Wvb;
    const float* bias = mat == 0 ? bq : mat == 1 ? bk : bv;

    const int arow = rt * 64 + w * 16 + l15;
    f32x4 acc[4] = {};
#pragma unroll
    for (int ks = 0; ks < 8; ++ks) {
        bf16x8 af = *reinterpret_cast<const bf16x8*>(&A[(size_t)arow * 256 + ks * 32 + 8 * g]);
#pragma unroll
        for (int c = 0; c < 4; ++c) {
            const int col = colbase + 16 * c + l15;
            bf16x8 wf = *reinterpret_cast<const bf16x8*>(&W[(size_t)col * 256 + ks * 32 + 8 * g]);
            acc[c] = __builtin_amdgcn_mfma_f32_16x16x32_bf16(af, wf, acc[c], 0, 0, 0);
        }
    }

#pragma unroll
    for (int c = 0; c < 4; ++c) {
        const int col = colbase + 16 * c + l15;
        const float bv_ = bias[col];
#pragma unroll
        for (int r = 0; r < 4; ++r) {
            const int m = rt * 64 + w * 16 + 4 * g + r;
            const float v = acc[c][r] + bv_;
            const int head = col >> 5, d = col & 31;
            const int bb = m >> 12, seq = m & 4095;
            const size_t bhbase = (size_t)(bb * NH + head) * (SEQ * DK);
            if (mat == 0) {
                Qb[bhbase + (size_t)seq * 32 + d] = f2bf(v * QS2);
            } else if (mat == 1) {
                const int t = seq >> 6, s = (seq >> 5) & 1, lk = seq & 31;
                const int hh = (d >> 4) & 1, gk = (d >> 3) & 1, jk = d & 7;
                Kblk[bhbase + t * 2048 + (s * 2 + hh) * 512 + (gk * 32 + lk) * 8 + jk] = f2bf(v);
            } else {
                const int t = seq >> 6, w6 = seq & 63;
                const int c2 = w6 >> 4, gv = (w6 >> 2) & 1, jv = ((w6 >> 3) & 1) * 4 + (w6 & 3);
                Vblk[bhbase + t * 2048 + c2 * 512 + (gv * 32 + d) * 8 + jv] = f2bf(v);
            }
        }
    }
}

// ---------------- flash attention: R13 structure + Z0 hoist + setprio ----------------
// 32 q-rows/wave, key-split x4, grid 2048, no dbuf. Issue-bound: cut v_movs, boost MFMA waves.
__global__ __launch_bounds__(256) void attn_kernel(
    const short* __restrict__ Qb, const short* __restrict__ Kblk,
    const short* __restrict__ Vblk, short* __restrict__ AOb)
{
    __shared__ float accL[3][64][17];  // waves 1..3 publish 16 acc + ls; stride 17 -> 2-way max (free)

    const int bid = ((int)blockIdx.x & 7) * 256 + ((int)blockIdx.x >> 3);  // XCD swizzle (2048 = 8*256)
    const int qt = bid & 127;
    const int bh = bid >> 7;  // each XCD serves exactly 2 bh -> 1MB KV in its L2
    const int b = bh >> 3, h = bh & 7;
    const int w = threadIdx.x >> 6;  // key-quarter
    const int l = threadIdx.x & 63;
    const int l31 = l & 31, g1 = l >> 5;

    const short* Qh = Qb + (size_t)bh * (SEQ * DK);
    const int q0 = qt * 32;
    const bf16x8 qf0 = *(const bf16x8*)&Qh[(size_t)(q0 + l31) * 32 + g1 * 8];
    const bf16x8 qf1 = *(const bf16x8*)&Qh[(size_t)(q0 + l31) * 32 + 16 + g1 * 8];

    const char* kp = (const char*)Kblk + (size_t)bh * 262144 + (size_t)w * 65536 + l * 16;
    const char* vp = (const char*)Vblk + (size_t)bh * 262144 + (size_t)w * 65536 + l * 16;

    f32x16 acc;
#pragma unroll
    for (int r = 0; r < 16; ++r) acc[r] = 0.f;
    f32x16 Z0;  // loop-invariant zero seed: kills per-tile zero-init movs (R6-proven)
#pragma unroll
    for (int r = 0; r < 16; ++r) Z0[r] = 0.f;
    // keep Z0 live so the compiler doesn't re-materialize per iteration
    asm volatile("" : "+v"(Z0));
    f32x4 ls4 = {0.f, 0.f, 0.f, 0.f};

    for (int t = 0; t < 16; ++t) {
        bf16x8 K0 = *(const bf16x8*)(kp);        bf16x8 K1 = *(const bf16x8*)(kp + 1024);
        bf16x8 K2 = *(const bf16x8*)(kp + 2048); bf16x8 K3 = *(const bf16x8*)(kp + 3072);
        bf16x8 V0 = *(const bf16x8*)(vp);        bf16x8 V1 = *(const bf16x8*)(vp + 1024);
        bf16x8 V2 = *(const bf16x8*)(vp + 2048); bf16x8 V3 = *(const bf16x8*)(vp + 3072);
        kp += 4096;
        vp += 4096;

#pragma unroll
        for (int s = 0; s < 2; ++s) {
            __builtin_amdgcn_s_setprio(1);
            f32x16 z = __builtin_amdgcn_mfma_f32_32x32x16_bf16(s ? K3 : K1, qf1, Z0, 0, 0, 0);
            z = __builtin_amdgcn_mfma_f32_32x32x16_bf16(s ? K2 : K0, qf0, z, 0, 0, 0);
            __builtin_amdgcn_s_setprio(0);
            f32x16 e;
#pragma unroll
            for (int r = 0; r < 16; ++r) e[r] = __builtin_amdgcn_exp2f(z[r]);
            const f32x4* e4 = (const f32x4*)&e;
            ls4 += e4[0];
            ls4 += e4[1];
            ls4 += e4[2];
            ls4 += e4[3];
            union { unsigned u[8]; bf16x8 v[2]; } pk;
#pragma unroll
            for (int i = 0; i < 8; ++i)
                asm("v_cvt_pk_bf16_f32 %0, %1, %2" : "=v"(pk.u[i]) : "v"(e[2 * i]), "v"(e[2 * i + 1]));
            __builtin_amdgcn_s_setprio(1);
            acc = __builtin_amdgcn_mfma_f32_32x32x16_bf16(pk.v[0], s ? V2 : V0, acc, 0, 0, 0);
            acc = __builtin_amdgcn_mfma_f32_32x32x16_bf16(pk.v[1], s ? V3 : V1, acc, 0, 0, 0);
            __builtin_amdgcn_s_setprio(0);
        }
    }

    // per-wave row sums: lane l and partner l^32 cover complementary keys of this quarter
    float ls = (ls4[0] + ls4[1]) + (ls4[2] + ls4[3]);
    ls += __shfl_xor(ls, 32);

    // combine the four key-quarters (waves 1..3 publish, wave 0 reduces + stores)
    if (w > 0) {
#pragma unroll
        for (int r = 0; r < 16; ++r) accL[w - 1][l][r] = acc[r];
        accL[w - 1][l][16] = ls;
    }
    __syncthreads();
    if (w == 0) {
#pragma unroll
        for (int wv = 0; wv < 3; ++wv) {
#pragma unroll
            for (int r = 0; r < 16; ++r) acc[r] += accL[wv][l][r];
            ls += accL[wv][l][16];
        }
        const float inv = 1.0f / ls;  // per-lane, for q-row = l&31
#pragma unroll
        for (int r = 0; r < 16; ++r) {
            const int ql = (r & 3) + 8 * (r >> 2) + 4 * g1;
            const float invq = __shfl(inv, ql);
            AOb[((size_t)b * SEQ + q0 + ql) * D_MODEL + h * DK + l31] = f2bf(acc[r] * invq);
        }
    }
}

// ---------------- output projection (R5-proven, frozen): bf16 AO @ Wo^T + bo, fp32 out ----------------
__global__ __launch_bounds__(256) void out_gemm(
    const short* __restrict__ AOb, const short* __restrict__ Wob,
    const float* __restrict__ bo, float* __restrict__ out)
{
    const int ct = blockIdx.x, rt = blockIdx.y;
    const int tid = threadIdx.x;
    const int w = tid >> 6, l = tid & 63, l15 = l & 15, g = l >> 4;
    const int arow = rt * 64 + w * 16 + l15;

    f32x4 acc[4] = {};
#pragma unroll
    for (int ks = 0; ks < 8; ++ks) {
        bf16x8 af = *(const bf16x8*)&AOb[(size_t)arow * 256 + ks * 32 + 8 * g];
#pragma unroll
        for (int c = 0; c < 4; ++c) {
            const int col = ct * 64 + 16 * c + l15;
            bf16x8 wf = *(const bf16x8*)&Wob[(size_t)col * 256 + ks * 32 + 8 * g];
            acc[c] = __builtin_amdgcn_mfma_f32_16x16x32_bf16(af, wf, acc[c], 0, 0, 0);
        }
    }
#pragma unroll
    for (int c = 0; c < 4; ++c) {
        const int col = ct * 64 + 16 * c + l15;
        const float bv_ = bo[col];
#pragma unroll
        for (int r = 0; r < 4; ++r) {
            const int m = rt * 64 + w * 16 + 4 * g + r;
            out[(size_t)m * 256 + col] = acc[c][r] + bv_;
        }
    }
}

extern "C" void kernel_launch(void* const* d_in, const int* in_sizes, int n_in,
                              void* d_out, int out_size, void* d_ws, size_t ws_size,
                              hipStream_t stream) {
    const float* x  = (const float*)d_in[0];
    const float* Wq = (const float*)d_in[1];
    const float* bq = (const float*)d_in[2];
    const float* Wk = (const float*)d_in[3];
    const float* bk = (const float*)d_in[4];
    const float* Wv = (const float*)d_in[5];
    const float* bv = (const float*)d_in[6];
    const float* Wo = (const float*)d_in[7];
    const float* bo = (const float*)d_in[8];
    float* out = (float*)d_out;

    char* ws = (char*)d_ws;
    const size_t MB = 1 << 20, KB = 1 << 10;
    short* xb   = (short*)(ws);                      // 4 MB [8192][256] bf16
    short* Wqb  = (short*)(ws + 4 * MB);             // 128 KB each
    short* Wkb  = (short*)(ws + 4 * MB + 128 * KB);
    short* Wvb  = (short*)(ws + 4 * MB + 256 * KB);
    short* Wob  = (short*)(ws + 4 * MB + 384 * KB);
    short* Qb   = (short*)(ws + 4 * MB + 512 * KB);  // 4 MB [bh][seq][32]
    short* Kblk = (short*)(ws + 8 * MB + 512 * KB);  // 4 MB fragment-order
    short* Vblk = (short*)(ws + 12 * MB + 512 * KB); // 4 MB fragment-order
    short* AOb  = (short*)(ws + 16 * MB + 512 * KB); // 4 MB [8192][256] bf16
    // total 20.5 MB == proven footprint

    cvt_all<<<2304, 256, 0, stream>>>(x, xb, Wq, Wk, Wv, Wo, Wqb, Wkb, Wvb, Wob);

    dim3 gq(12, 128);
    qkv_gemm<<<gq, 256, 0, stream>>>(xb, Wqb, Wkb, Wvb, bq, bk, bv, Qb, Kblk, Vblk);

    attn_kernel<<<2048, 256, 0, stream>>>(Qb, Kblk, Vblk, AOb);

    dim3 go(4, 128);
    out_gemm<<<go, 256, 0, stream>>>(AOb, Wob, bo, out);
}

// Round 15
// 110.893 us; speedup vs baseline: 1.0080x; 1.0080x over previous
//
#include <hip/hip_runtime.h>

#define D_MODEL 256
#define NH 8
#define DK 32
#define SEQ 4096
#define BATCH 2
#define M_ROWS (BATCH * SEQ)  // 8192
#define QS2 0.25503486f  // (1/sqrt(32))*log2(e): softmax scale + exp->exp2, folded into Q

typedef __attribute__((ext_vector_type(8))) short bf16x8;
typedef __attribute__((ext_vector_type(4))) short s16x4;
typedef __attribute__((ext_vector_type(4))) float f32x4;
typedef __attribute__((ext_vector_type(16))) float f32x16;

static __device__ __forceinline__ short f2bf(float f) {
    unsigned u = __float_as_uint(f);
    u += 0x7fff + ((u >> 16) & 1);  // RNE
    return (short)(u >> 16);
}

// ---------------- fp32 -> bf16 converts: x (2048 blk) + 4 weights (256 blk), one launch ----------------
__global__ void cvt_all(const float* __restrict__ x, short* __restrict__ xb,
                        const float* __restrict__ W0, const float* __restrict__ W1,
                        const float* __restrict__ W2, const float* __restrict__ W3,
                        short* __restrict__ D0, short* __restrict__ D1,
                        short* __restrict__ D2, short* __restrict__ D3) {
    const int blk = blockIdx.x;
    const float* s;
    short* d;
    int i;
    if (blk < 2048) {
        s = x; d = xb; i = blk * blockDim.x + threadIdx.x;
    } else {
        const int seg = (blk - 2048) >> 6;
        i = ((blk - 2048) & 63) * blockDim.x + threadIdx.x;
        s = seg == 0 ? W0 : seg == 1 ? W1 : seg == 2 ? W2 : W3;
        d = seg == 0 ? D0 : seg == 1 ? D1 : seg == 2 ? D2 : D3;
    }
    float4 v = reinterpret_cast<const float4*>(s)[i];
    s16x4 o;
    o.x = f2bf(v.x); o.y = f2bf(v.y); o.z = f2bf(v.z); o.w = f2bf(v.w);
    reinterpret_cast<s16x4*>(d)[i] = o;
}

// ---------------- QKV projection (R13-proven, frozen) ----------------
// Q: [bh][seq][32] bf16 pre-scaled by QS2.
// K: Kblk[bh][t][s*2+hh][lane][8]: granule(lane l) = K[t*64+s*32+(l&31)][d = 16*hh+8*(l>>5) .. +8]
// V: Vblk[bh][t][c][lane][8]: elem j = V[t*64 + 16c + 8*(j>>2) + 4*(l>>5) + (j&3)][d = l&31]
__global__ __launch_bounds__(256) void qkv_gemm(
    const short* __restrict__ A,
    const short* __restrict__ Wqb, const short* __restrict__ Wkb, const short* __restrict__ Wvb,
    const float* __restrict__ bq, const float* __restrict__ bk, const float* __restrict__ bv,
    short* __restrict__ Qb, short* __restrict__ Kblk, short* __restrict__ Vblk)
{
    const int ct = blockIdx.x;   // 0..11 = mat*4 + coltile
    const int rt = blockIdx.y;   // 0..127
    const int tid = threadIdx.x;
    const int w = tid >> 6, l = tid & 63, l15 = l & 15, g = l >> 4;
    const int mat = ct >> 2;
    const int colbase = (ct & 3) * 64;
    const short* W = mat == 0 ? Wqb : mat == 1 ? Wkb : Wvb;
    const float* bias = mat == 0 ? bq : mat == 1 ? bk : bv;

    const int arow = rt * 64 + w * 16 + l15;
    f32x4 acc[4] = {};
#pragma unroll
    for (int ks = 0; ks < 8; ++ks) {
        bf16x8 af = *reinterpret_cast<const bf16x8*>(&A[(size_t)arow * 256 + ks * 32 + 8 * g]);
#pragma unroll
        for (int c = 0; c < 4; ++c) {
            const int col = colbase + 16 * c + l15;
            bf16x8 wf = *reinterpret_cast<const bf16x8*>(&W[(size_t)col * 256 + ks * 32 + 8 * g]);
            acc[c] = __builtin_amdgcn_mfma_f32_16x16x32_bf16(af, wf, acc[c], 0, 0, 0);
        }
    }

#pragma unroll
    for (int c = 0; c < 4; ++c) {
        const int col = colbase + 16 * c + l15;
        const float bv_ = bias[col];
#pragma unroll
        for (int r = 0; r < 4; ++r) {
            const int m = rt * 64 + w * 16 + 4 * g + r;
            const float v = acc[c][r] + bv_;
            const int head = col >> 5, d = col & 31;
            const int bb = m >> 12, seq = m & 4095;
            const size_t bhbase = (size_t)(bb * NH + head) * (SEQ * DK);
            if (mat == 0) {
                Qb[bhbase + (size_t)seq * 32 + d] = f2bf(v * QS2);
            } else if (mat == 1) {
                const int t = seq >> 6, s = (seq >> 5) & 1, lk = seq & 31;
                const int hh = (d >> 4) & 1, gk = (d >> 3) & 1, jk = d & 7;
                Kblk[bhbase + t * 2048 + (s * 2 + hh) * 512 + (gk * 32 + lk) * 8 + jk] = f2bf(v);
            } else {
                const int t = seq >> 6, w6 = seq & 63;
                const int c2 = w6 >> 4, gv = (w6 >> 2) & 1, jv = ((w6 >> 3) & 1) * 4 + (w6 & 3);
                Vblk[bhbase + t * 2048 + c2 * 512 + (gv * 32 + d) * 8 + jv] = f2bf(v);
            }
        }
    }
}

// ---------------- flash attention: R13 structure + clean Z0 hoist (no asm, no setprio) ----------------
// 32 q-rows/wave, key-split x4, grid 2048, no dbuf, ptr-increment addressing.
__global__ __launch_bounds__(256) void attn_kernel(
    const short* __restrict__ Qb, const short* __restrict__ Kblk,
    const short* __restrict__ Vblk, short* __restrict__ AOb)
{
    __shared__ float accL[3][64][17];  // waves 1..3 publish 16 acc + ls; stride 17 -> 2-way max (free)

    const int bid = ((int)blockIdx.x & 7) * 256 + ((int)blockIdx.x >> 3);  // XCD swizzle (2048 = 8*256)
    const int qt = bid & 127;
    const int bh = bid >> 7;  // each XCD serves exactly 2 bh -> 1MB KV in its L2
    const int b = bh >> 3, h = bh & 7;
    const int w = threadIdx.x >> 6;  // key-quarter
    const int l = threadIdx.x & 63;
    const int l31 = l & 31, g1 = l >> 5;

    const short* Qh = Qb + (size_t)bh * (SEQ * DK);
    const int q0 = qt * 32;
    const bf16x8 qf0 = *(const bf16x8*)&Qh[(size_t)(q0 + l31) * 32 + g1 * 8];
    const bf16x8 qf1 = *(const bf16x8*)&Qh[(size_t)(q0 + l31) * 32 + 16 + g1 * 8];

    const char* kp = (const char*)Kblk + (size_t)bh * 262144 + (size_t)w * 65536 + l * 16;
    const char* vp = (const char*)Vblk + (size_t)bh * 262144 + (size_t)w * 65536 + l * 16;

    f32x16 acc;
#pragma unroll
    for (int r = 0; r < 16; ++r) acc[r] = 0.f;
    f32x16 Z0;  // loop-invariant zero seed (R6/R8-proven form: plain, no liveness hack)
#pragma unroll
    for (int r = 0; r < 16; ++r) Z0[r] = 0.f;
    f32x4 ls4 = {0.f, 0.f, 0.f, 0.f};

    for (int t = 0; t < 16; ++t) {
        bf16x8 K0 = *(const bf16x8*)(kp);        bf16x8 K1 = *(const bf16x8*)(kp + 1024);
        bf16x8 K2 = *(const bf16x8*)(kp + 2048); bf16x8 K3 = *(const bf16x8*)(kp + 3072);
        bf16x8 V0 = *(const bf16x8*)(vp);        bf16x8 V1 = *(const bf16x8*)(vp + 1024);
        bf16x8 V2 = *(const bf16x8*)(vp + 2048); bf16x8 V3 = *(const bf16x8*)(vp + 3072);
        kp += 4096;
        vp += 4096;

#pragma unroll
        for (int s = 0; s < 2; ++s) {
            f32x16 z = __builtin_amdgcn_mfma_f32_32x32x16_bf16(s ? K3 : K1, qf1, Z0, 0, 0, 0);
            z = __builtin_amdgcn_mfma_f32_32x32x16_bf16(s ? K2 : K0, qf0, z, 0, 0, 0);
            f32x16 e;
#pragma unroll
            for (int r = 0; r < 16; ++r) e[r] = __builtin_amdgcn_exp2f(z[r]);
            const f32x4* e4 = (const f32x4*)&e;
            ls4 += e4[0];
            ls4 += e4[1];
            ls4 += e4[2];
            ls4 += e4[3];
            union { unsigned u[8]; bf16x8 v[2]; } pk;
#pragma unroll
            for (int i = 0; i < 8; ++i)
                asm("v_cvt_pk_bf16_f32 %0, %1, %2" : "=v"(pk.u[i]) : "v"(e[2 * i]), "v"(e[2 * i + 1]));
            acc = __builtin_amdgcn_mfma_f32_32x32x16_bf16(pk.v[0], s ? V2 : V0, acc, 0, 0, 0);
            acc = __builtin_amdgcn_mfma_f32_32x32x16_bf16(pk.v[1], s ? V3 : V1, acc, 0, 0, 0);
        }
    }

    // per-wave row sums: lane l and partner l^32 cover complementary keys of this quarter
    float ls = (ls4[0] + ls4[1]) + (ls4[2] + ls4[3]);
    ls += __shfl_xor(ls, 32);

    // combine the four key-quarters (waves 1..3 publish, wave 0 reduces + stores)
    if (w > 0) {
#pragma unroll
        for (int r = 0; r < 16; ++r) accL[w - 1][l][r] = acc[r];
        accL[w - 1][l][16] = ls;
    }
    __syncthreads();
    if (w == 0) {
#pragma unroll
        for (int wv = 0; wv < 3; ++wv) {
#pragma unroll
            for (int r = 0; r < 16; ++r) acc[r] += accL[wv][l][r];
            ls += accL[wv][l][16];
        }
        const float inv = 1.0f / ls;  // per-lane, for q-row = l&31
#pragma unroll
        for (int r = 0; r < 16; ++r) {
            const int ql = (r & 3) + 8 * (r >> 2) + 4 * g1;
            const float invq = __shfl(inv, ql);
            AOb[((size_t)b * SEQ + q0 + ql) * D_MODEL + h * DK + l31] = f2bf(acc[r] * invq);
        }
    }
}

// ---------------- output projection (R5-proven, frozen): bf16 AO @ Wo^T + bo, fp32 out ----------------
__global__ __launch_bounds__(256) void out_gemm(
    const short* __restrict__ AOb, const short* __restrict__ Wob,
    const float* __restrict__ bo, float* __restrict__ out)
{
    const int ct = blockIdx.x, rt = blockIdx.y;
    const int tid = threadIdx.x;
    const int w = tid >> 6, l = tid & 63, l15 = l & 15, g = l >> 4;
    const int arow = rt * 64 + w * 16 + l15;

    f32x4 acc[4] = {};
#pragma unroll
    for (int ks = 0; ks < 8; ++ks) {
        bf16x8 af = *(const bf16x8*)&AOb[(size_t)arow * 256 + ks * 32 + 8 * g];
#pragma unroll
        for (int c = 0; c < 4; ++c) {
            const int col = ct * 64 + 16 * c + l15;
            bf16x8 wf = *(const bf16x8*)&Wob[(size_t)col * 256 + ks * 32 + 8 * g];
            acc[c] = __builtin_amdgcn_mfma_f32_16x16x32_bf16(af, wf, acc[c], 0, 0, 0);
        }
    }
#pragma unroll
    for (int c = 0; c < 4; ++c) {
        const int col = ct * 64 + 16 * c + l15;
        const float bv_ = bo[col];
#pragma unroll
        for (int r = 0; r < 4; ++r) {
            const int m = rt * 64 + w * 16 + 4 * g + r;
            out[(size_t)m * 256 + col] = acc[c][r] + bv_;
        }
    }
}

extern "C" void kernel_launch(void* const* d_in, const int* in_sizes, int n_in,
                              void* d_out, int out_size, void* d_ws, size_t ws_size,
                              hipStream_t stream) {
    const float* x  = (const float*)d_in[0];
    const float* Wq = (const float*)d_in[1];
    const float* bq = (const float*)d_in[2];
    const float* Wk = (const float*)d_in[3];
    const float* bk = (const float*)d_in[4];
    const float* Wv = (const float*)d_in[5];
    const float* bv = (const float*)d_in[6];
    const float* Wo = (const float*)d_in[7];
    const float* bo = (const float*)d_in[8];
    float* out = (float*)d_out;

    char* ws = (char*)d_ws;
    const size_t MB = 1 << 20, KB = 1 << 10;
    short* xb   = (short*)(ws);                      // 4 MB [8192][256] bf16
    short* Wqb  = (short*)(ws + 4 * MB);             // 128 KB each
    short* Wkb  = (short*)(ws + 4 * MB + 128 * KB);
    short* Wvb  = (short*)(ws + 4 * MB + 256 * KB);
    short* Wob  = (short*)(ws + 4 * MB + 384 * KB);
    short* Qb   = (short*)(ws + 4 * MB + 512 * KB);  // 4 MB [bh][seq][32]
    short* Kblk = (short*)(ws + 8 * MB + 512 * KB);  // 4 MB fragment-order
    short* Vblk = (short*)(ws + 12 * MB + 512 * KB); // 4 MB fragment-order
    short* AOb  = (short*)(ws + 16 * MB + 512 * KB); // 4 MB [8192][256] bf16
    // total 20.5 MB == proven footprint

    cvt_all<<<2304, 256, 0, stream>>>(x, xb, Wq, Wk, Wv, Wo, Wqb, Wkb, Wvb, Wob);

    dim3 gq(12, 128);
    qkv_gemm<<<gq, 256, 0, stream>>>(xb, Wqb, Wkb, Wvb, bq, bk, bv, Qb, Kblk, Vblk);

    attn_kernel<<<2048, 256, 0, stream>>>(Qb, Kblk, Vblk, AOb);

    dim3 go(4, 128);
    out_gemm<<<go, 256, 0, stream>>>(AOb, Wob, bo, out);
}

// Round 16
// 109.650 us; speedup vs baseline: 1.0194x; 1.0113x over previous
//
#include <hip/hip_runtime.h>

#define D_MODEL 256
#define NH 8
#define DK 32
#define SEQ 4096
#define BATCH 2
#define M_ROWS (BATCH * SEQ)  // 8192
#define QS2 0.25503486f  // (1/sqrt(32))*log2(e): softmax scale + exp->exp2, folded into Q

typedef __attribute__((ext_vector_type(8))) short bf16x8;
typedef __attribute__((ext_vector_type(4))) short s16x4;
typedef __attribute__((ext_vector_type(4))) float f32x4;
typedef __attribute__((ext_vector_type(16))) float f32x16;

static __device__ __forceinline__ short f2bf(float f) {
    unsigned u = __float_as_uint(f);
    u += 0x7fff + ((u >> 16) & 1);  // RNE
    return (short)(u >> 16);
}

// ---------------- fp32 -> bf16 converts: x (2048 blk) + 4 weights (256 blk), one launch ----------------
__global__ void cvt_all(const float* __restrict__ x, short* __restrict__ xb,
                        const float* __restrict__ W0, const float* __restrict__ W1,
                        const float* __restrict__ W2, const float* __restrict__ W3,
                        short* __restrict__ D0, short* __restrict__ D1,
                        short* __restrict__ D2, short* __restrict__ D3) {
    const int blk = blockIdx.x;
    const float* s;
    short* d;
    int i;
    if (blk < 2048) {
        s = x; d = xb; i = blk * blockDim.x + threadIdx.x;
    } else {
        const int seg = (blk - 2048) >> 6;
        i = ((blk - 2048) & 63) * blockDim.x + threadIdx.x;
        s = seg == 0 ? W0 : seg == 1 ? W1 : seg == 2 ? W2 : W3;
        d = seg == 0 ? D0 : seg == 1 ? D1 : seg == 2 ? D2 : D3;
    }
    float4 v = reinterpret_cast<const float4*>(s)[i];
    s16x4 o;
    o.x = f2bf(v.x); o.y = f2bf(v.y); o.z = f2bf(v.z); o.w = f2bf(v.w);
    reinterpret_cast<s16x4*>(d)[i] = o;
}

// ---------------- QKV projection (R13-proven, frozen) ----------------
// Q: [bh][seq][32] bf16 pre-scaled by QS2.
// K: Kblk[bh][t][s*2+hh][lane][8]: granule(lane l) = K[t*64+s*32+(l&31)][d = 16*hh+8*(l>>5) .. +8]
// V: Vblk[bh][t][c][lane][8]: elem j = V[t*64 + 16c + 8*(j>>2) + 4*(l>>5) + (j&3)][d = l&31]
__global__ __launch_bounds__(256) void qkv_gemm(
    const short* __restrict__ A,
    const short* __restrict__ Wqb, const short* __restrict__ Wkb, const short* __restrict__ Wvb,
    const float* __restrict__ bq, const float* __restrict__ bk, const float* __restrict__ bv,
    short* __restrict__ Qb, short* __restrict__ Kblk, short* __restrict__ Vblk)
{
    const int ct = blockIdx.x;   // 0..11 = mat*4 + coltile
    const int rt = blockIdx.y;   // 0..127
    const int tid = threadIdx.x;
    const int w = tid >> 6, l = tid & 63, l15 = l & 15, g = l >> 4;
    const int mat = ct >> 2;
    const int colbase = (ct & 3) * 64;
    const short* W = mat == 0 ? Wqb : mat == 1 ? Wkb : Wvb;
    const float* bias = mat == 0 ? bq : mat == 1 ? bk : bv;

    const int arow = rt * 64 + w * 16 + l15;
    f32x4 acc[4] = {};
#pragma unroll
    for (int ks = 0; ks < 8; ++ks) {
        bf16x8 af = *reinterpret_cast<const bf16x8*>(&A[(size_t)arow * 256 + ks * 32 + 8 * g]);
#pragma unroll
        for (int c = 0; c < 4; ++c) {
            const int col = colbase + 16 * c + l15;
            bf16x8 wf = *reinterpret_cast<const bf16x8*>(&W[(size_t)col * 256 + ks * 32 + 8 * g]);
            acc[c] = __builtin_amdgcn_mfma_f32_16x16x32_bf16(af, wf, acc[c], 0, 0, 0);
        }
    }

#pragma unroll
    for (int c = 0; c < 4; ++c) {
        const int col = colbase + 16 * c + l15;
        const float bv_ = bias[col];
#pragma unroll
        for (int r = 0; r < 4; ++r) {
            const int m = rt * 64 + w * 16 + 4 * g + r;
            const float v = acc[c][r] + bv_;
            const int head = col >> 5, d = col & 31;
            const int bb = m >> 12, seq = m & 4095;
            const size_t bhbase = (size_t)(bb * NH + head) * (SEQ * DK);
            if (mat == 0) {
                Qb[bhbase + (size_t)seq * 32 + d] = f2bf(v * QS2);
            } else if (mat == 1) {
                const int t = seq >> 6, s = (seq >> 5) & 1, lk = seq & 31;
                const int hh = (d >> 4) & 1, gk = (d >> 3) & 1, jk = d & 7;
                Kblk[bhbase + t * 2048 + (s * 2 + hh) * 512 + (gk * 32 + lk) * 8 + jk] = f2bf(v);
            } else {
                const int t = seq >> 6, w6 = seq & 63;
                const int c2 = w6 >> 4, gv = (w6 >> 2) & 1, jv = ((w6 >> 3) & 1) * 4 + (w6 & 3);
                Vblk[bhbase + t * 2048 + c2 * 512 + (gv * 32 + d) * 8 + jv] = f2bf(v);
            }
        }
    }
}

// ---------------- flash attention: R15 + acc-register diet ----------------
// 32 q-rows/wave, key-split x4, grid 2048. Diet: exp in-place (no e array),
// cvt_pk direct from z, V loads split per s-half. Target: ~150 unified regs -> 3+ waves/SIMD.
__global__ __launch_bounds__(256) void attn_kernel(
    const short* __restrict__ Qb, const short* __restrict__ Kblk,
    const short* __restrict__ Vblk, short* __restrict__ AOb)
{
    __shared__ float accL[3][64][17];  // waves 1..3 publish 16 acc + ls; stride 17 -> 2-way max (free)

    const int bid = ((int)blockIdx.x & 7) * 256 + ((int)blockIdx.x >> 3);  // XCD swizzle (2048 = 8*256)
    const int qt = bid & 127;
    const int bh = bid >> 7;  // each XCD serves exactly 2 bh -> 1MB KV in its L2
    const int b = bh >> 3, h = bh & 7;
    const int w = threadIdx.x >> 6;  // key-quarter
    const int l = threadIdx.x & 63;
    const int l31 = l & 31, g1 = l >> 5;

    const short* Qh = Qb + (size_t)bh * (SEQ * DK);
    const int q0 = qt * 32;
    const bf16x8 qf0 = *(const bf16x8*)&Qh[(size_t)(q0 + l31) * 32 + g1 * 8];
    const bf16x8 qf1 = *(const bf16x8*)&Qh[(size_t)(q0 + l31) * 32 + 16 + g1 * 8];

    const char* kp = (const char*)Kblk + (size_t)bh * 262144 + (size_t)w * 65536 + l * 16;
    const char* vp = (const char*)Vblk + (size_t)bh * 262144 + (size_t)w * 65536 + l * 16;

    f32x16 acc;
#pragma unroll
    for (int r = 0; r < 16; ++r) acc[r] = 0.f;
    f32x16 Z0;  // loop-invariant zero seed
#pragma unroll
    for (int r = 0; r < 16; ++r) Z0[r] = 0.f;
    f32x4 ls4 = {0.f, 0.f, 0.f, 0.f};

    for (int t = 0; t < 16; ++t) {
        bf16x8 K0 = *(const bf16x8*)(kp);        bf16x8 K1 = *(const bf16x8*)(kp + 1024);
        bf16x8 K2 = *(const bf16x8*)(kp + 2048); bf16x8 K3 = *(const bf16x8*)(kp + 3072);

#pragma unroll
        for (int s = 0; s < 2; ++s) {
            // V pair for this s-half only: latency hidden under QK^T + exp chain
            bf16x8 Va = *(const bf16x8*)(vp + (s ? 2048 : 0));
            bf16x8 Vb = *(const bf16x8*)(vp + (s ? 3072 : 1024));
            f32x16 z = __builtin_amdgcn_mfma_f32_32x32x16_bf16(s ? K3 : K1, qf1, Z0, 0, 0, 0);
            z = __builtin_amdgcn_mfma_f32_32x32x16_bf16(s ? K2 : K0, qf0, z, 0, 0, 0);
            // exp in place: z becomes P (no separate e array -> -16 live regs)
#pragma unroll
            for (int r = 0; r < 16; ++r) z[r] = __builtin_amdgcn_exp2f(z[r]);
            const f32x4* z4 = (const f32x4*)&z;
            ls4 += z4[0];
            ls4 += z4[1];
            ls4 += z4[2];
            ls4 += z4[3];
            union { unsigned u[8]; bf16x8 v[2]; } pk;
#pragma unroll
            for (int i = 0; i < 8; ++i)
                asm("v_cvt_pk_bf16_f32 %0, %1, %2" : "=v"(pk.u[i]) : "v"(z[2 * i]), "v"(z[2 * i + 1]));
            acc = __builtin_amdgcn_mfma_f32_32x32x16_bf16(pk.v[0], Va, acc, 0, 0, 0);
            acc = __builtin_amdgcn_mfma_f32_32x32x16_bf16(pk.v[1], Vb, acc, 0, 0, 0);
        }
        kp += 4096;
        vp += 4096;
    }

    // per-wave row sums: lane l and partner l^32 cover complementary keys of this quarter
    float ls = (ls4[0] + ls4[1]) + (ls4[2] + ls4[3]);
    ls += __shfl_xor(ls, 32);

    // combine the four key-quarters (waves 1..3 publish, wave 0 reduces + stores)
    if (w > 0) {
#pragma unroll
        for (int r = 0; r < 16; ++r) accL[w - 1][l][r] = acc[r];
        accL[w - 1][l][16] = ls;
    }
    __syncthreads();
    if (w == 0) {
#pragma unroll
        for (int wv = 0; wv < 3; ++wv) {
#pragma unroll
            for (int r = 0; r < 16; ++r) acc[r] += accL[wv][l][r];
            ls += accL[wv][l][16];
        }
        const float inv = 1.0f / ls;  // per-lane, for q-row = l&31
#pragma unroll
        for (int r = 0; r < 16; ++r) {
            const int ql = (r & 3) + 8 * (r >> 2) + 4 * g1;
            const float invq = __shfl(inv, ql);
            AOb[((size_t)b * SEQ + q0 + ql) * D_MODEL + h * DK + l31] = f2bf(acc[r] * invq);
        }
    }
}

// ---------------- output projection (R5-proven, frozen): bf16 AO @ Wo^T + bo, fp32 out ----------------
__global__ __launch_bounds__(256) void out_gemm(
    const short* __restrict__ AOb, const short* __restrict__ Wob,
    const float* __restrict__ bo, float* __restrict__ out)
{
    const int ct = blockIdx.x, rt = blockIdx.y;
    const int tid = threadIdx.x;
    const int w = tid >> 6, l = tid & 63, l15 = l & 15, g = l >> 4;
    const int arow = rt * 64 + w * 16 + l15;

    f32x4 acc[4] = {};
#pragma unroll
    for (int ks = 0; ks < 8; ++ks) {
        bf16x8 af = *(const bf16x8*)&AOb[(size_t)arow * 256 + ks * 32 + 8 * g];
#pragma unroll
        for (int c = 0; c < 4; ++c) {
            const int col = ct * 64 + 16 * c + l15;
            bf16x8 wf = *(const bf16x8*)&Wob[(size_t)col * 256 + ks * 32 + 8 * g];
            acc[c] = __builtin_amdgcn_mfma_f32_16x16x32_bf16(af, wf, acc[c], 0, 0, 0);
        }
    }
#pragma unroll
    for (int c = 0; c < 4; ++c) {
        const int col = ct * 64 + 16 * c + l15;
        const float bv_ = bo[col];
#pragma unroll
        for (int r = 0; r < 4; ++r) {
            const int m = rt * 64 + w * 16 + 4 * g + r;
            out[(size_t)m * 256 + col] = acc[c][r] + bv_;
        }
    }
}

extern "C" void kernel_launch(void* const* d_in, const int* in_sizes, int n_in,
                              void* d_out, int out_size, void* d_ws, size_t ws_size,
                              hipStream_t stream) {
    const float* x  = (const float*)d_in[0];
    const float* Wq = (const float*)d_in[1];
    const float* bq = (const float*)d_in[2];
    const float* Wk = (const float*)d_in[3];
    const float* bk = (const float*)d_in[4];
    const float* Wv = (const float*)d_in[5];
    const float* bv = (const float*)d_in[6];
    const float* Wo = (const float*)d_in[7];
    const float* bo = (const float*)d_in[8];
    float* out = (float*)d_out;

    char* ws = (char*)d_ws;
    const size_t MB = 1 << 20, KB = 1 << 10;
    short* xb   = (short*)(ws);                      // 4 MB [8192][256] bf16
    short* Wqb  = (short*)(ws + 4 * MB);             // 128 KB each
    short* Wkb  = (short*)(ws + 4 * MB + 128 * KB);
    short* Wvb  = (short*)(ws + 4 * MB + 256 * KB);
    short* Wob  = (short*)(ws + 4 * MB + 384 * KB);
    short* Qb   = (short*)(ws + 4 * MB + 512 * KB);  // 4 MB [bh][seq][32]
    short* Kblk = (short*)(ws + 8 * MB + 512 * KB);  // 4 MB fragment-order
    short* Vblk = (short*)(ws + 12 * MB + 512 * KB); // 4 MB fragment-order
    short* AOb  = (short*)(ws + 16 * MB + 512 * KB); // 4 MB [8192][256] bf16
    // total 20.5 MB == proven footprint

    cvt_all<<<2304, 256, 0, stream>>>(x, xb, Wq, Wk, Wv, Wo, Wqb, Wkb, Wvb, Wob);

    dim3 gq(12, 128);
    qkv_gemm<<<gq, 256, 0, stream>>>(xb, Wqb, Wkb, Wvb, bq, bk, bv, Qb, Kblk, Vblk);

    attn_kernel<<<2048, 256, 0, stream>>>(Qb, Kblk, Vblk, AOb);

    dim3 go(4, 128);
    out_gemm<<<go, 256, 0, stream>>>(AOb, Wob, bo, out);
}